// Round 11
// baseline (150.356 us; speedup 1.0000x reference)
//
#include <hip/hip_runtime.h>
#include <hip/hip_bf16.h>

#define H_ 8
#define D_ 64
#define IN_ 512
#define B_ 4
#define N_ 2048
#define TOK_ (B_*N_)
// softmax in exp2 domain: scale * log2(e) (folded into Q at projection time)
#define CLOG2_ 0.18033688011112042f

typedef __attribute__((ext_vector_type(8))) short short8;
typedef __attribute__((ext_vector_type(4))) short bs4;
typedef __attribute__((ext_vector_type(4))) float f32x4;

__device__ __forceinline__ unsigned short f2bf(float f) {
  unsigned int u = __float_as_uint(f);
  u += 0x7FFFu + ((u >> 16) & 1u);
  return (unsigned short)(u >> 16);
}

// packed converts: v_cvt_pk_bf16_f32
__device__ __forceinline__ short8 cvt8(const float4 a, const float4 b) {
  union { short8 v; __hip_bfloat162 h[4]; } z;
  z.h[0] = __float22bfloat162_rn(make_float2(a.x, a.y));
  z.h[1] = __float22bfloat162_rn(make_float2(a.z, a.w));
  z.h[2] = __float22bfloat162_rn(make_float2(b.x, b.y));
  z.h[3] = __float22bfloat162_rn(make_float2(b.z, b.w));
  return z.v;
}

__device__ __forceinline__ bs4 pack4(float a, float b, float c, float d) {
  union { bs4 v; __hip_bfloat162 h[2]; } z;
  z.h[0] = __float22bfloat162_rn(make_float2(a, b));
  z.h[1] = __float22bfloat162_rn(make_float2(c, d));
  return z.v;
}

// Reassemble two K=16 P-fragments (keys nb*16+quad*4+r layout) into one K=32
// B-fragment (keys quad*8+j layout) with 4 lane-swaps.
__device__ __forceinline__ short8 assemble_p(bs4 pa, bs4 pb) {
  union { bs4 v; unsigned int w[2]; } A, B;
  A.v = pa; B.v = pb;
  auto s0 = __builtin_amdgcn_permlane32_swap(A.w[0], B.w[0], false, false);
  auto s1 = __builtin_amdgcn_permlane32_swap(A.w[1], B.w[1], false, false);
  auto t0 = __builtin_amdgcn_permlane16_swap(s0[0], s0[1], false, false);
  auto t1 = __builtin_amdgcn_permlane16_swap(s1[0], s1[1], false, false);
  union { short8 v; unsigned int w[4]; } R;
  R.w[0] = t0[0];   // j=0,1
  R.w[1] = t1[0];   // j=2,3
  R.w[2] = t0[1];   // j=4,5
  R.w[3] = t1[1];   // j=6,7
  return R.v;
}

// async global->LDS, 16B per lane; dest = wave-uniform base + lane*16
__device__ __forceinline__ void gld16(const unsigned short* g, unsigned short* l) {
  __builtin_amdgcn_global_load_lds(
      (const __attribute__((address_space(1))) void*)g,
      (__attribute__((address_space(3))) void*)l, 16, 0, 0);
}

// ---------------------------------------------------------------------------
// Kernel 0: WEIGHTS-ONLY fp32 -> bf16 convert (Wq, Wkv, Wo). 512 blocks.
// ---------------------------------------------------------------------------
__global__ __launch_bounds__(256) void conv_w_kernel(
    const float* __restrict__ Wq, const float* __restrict__ Wkv,
    const float* __restrict__ Wo,
    unsigned short* __restrict__ wbf, unsigned short* __restrict__ wobf)
{
  const int b = blockIdx.x;
  const float* src;
  unsigned short* dst;
  size_t base;
  if (b < 128)       { src = Wq;  dst = wbf;             base = (size_t)b * 2048; }
  else if (b < 384)  { src = Wkv; dst = wbf + 512 * 512; base = (size_t)(b - 128) * 2048; }
  else               { src = Wo;  dst = wobf;            base = (size_t)(b - 384) * 2048; }
  size_t i = base + (size_t)threadIdx.x * 8;
  float4 a = *(const float4*)(src + i);
  float4 c = *(const float4*)(src + i + 4);
  *(short8*)(dst + i) = cvt8(a, c);
}

// ---------------------------------------------------------------------------
// Kernel 1: QKV projection. A = x fp32 reg-staged (load->cvt_pk->ds_write);
// B = weights bf16 via gld16 (L2-fit). 128x128 tile, BK=32, double-buffered,
// 1 barrier/iter. Q pre-scaled by CLOG2_. Q,K -> [b,h,n,d]; V -> [b,h,d,n].
// XCD-chunked block swizzle (T1, bijective: 768%8==0).
// ---------------------------------------------------------------------------
__global__ __launch_bounds__(256) void qkv_gemm_kernel(
    const float* __restrict__ x, const unsigned short* __restrict__ wbf,
    unsigned short* __restrict__ qws, unsigned short* __restrict__ kws,
    unsigned short* __restrict__ vws)
{
  // staging: buf b at sm + b*8192 (A 4096 | B 4096 shorts); epilogue overlay 128*136
  __shared__ __attribute__((aligned(16))) unsigned short sm[128 * 136];

  const int lid = blockIdx.x + (blockIdx.y << 6);      // grid (64,12), 0..767
  const int swz = (lid & 7) * 96 + (lid >> 3);         // bijective XCD chunking
  const int t0 = (swz / 12) * 128;
  const int c0 = (swz % 12) * 128;                     // 0..1535 over [Wq|Wkv] rows
  const int cls = c0 >> 9;                             // 0=q 1=k 2=v

  const int tid = threadIdx.x;
  const int wave = tid >> 6, lane = tid & 63;
  const int quad = lane >> 4, l16 = lane & 15;
  const int wm = wave >> 1, wn = wave & 1;

  // staging source: row r = g*64 + tid>>2, granule gc = (tid&3)^(r&3)
  const int r_ = tid >> 2;
  const int gc = (tid & 3) ^ (r_ & 3);
  const float* asrc = x + (size_t)(t0 + r_) * IN_ + gc * 8;
  const unsigned short* bbase = wbf + (size_t)(c0 + r_) * IN_ + gc * 8;

  float4 ra[4];
  auto loadA = [&](int k0) {
    ra[0] = *(const float4*)(asrc + k0);
    ra[1] = *(const float4*)(asrc + k0 + 4);
    ra[2] = *(const float4*)(asrc + 64 * IN_ + k0);
    ra[3] = *(const float4*)(asrc + 64 * IN_ + k0 + 4);
  };
  auto writeA = [&](int buf) {
    unsigned short* sA = sm + buf * 8192;
    *(short8*)(sA + tid * 8)        = cvt8(ra[0], ra[1]);
    *(short8*)(sA + 2048 + tid * 8) = cvt8(ra[2], ra[3]);
  };
  auto stageB = [&](int k0, int buf) {
    unsigned short* sB = sm + buf * 8192 + 4096;
    gld16(bbase + k0,            sB + tid * 8);
    gld16(bbase + 64 * IN_ + k0, sB + 2048 + tid * 8);
  };

  f32x4 acc[4][4];
  #pragma unroll
  for (int i = 0; i < 4; i++)
    #pragma unroll
    for (int j = 0; j < 4; j++) acc[i][j] = (f32x4){0.f, 0.f, 0.f, 0.f};

  loadA(0); writeA(0); stageB(0, 0); loadA(32);   // regs hold A-tile 1

  for (int kt = 0; kt < 16; kt++) {
    __syncthreads();              // buf[kt&1] ready; prev reads of other buf done
    if (kt + 1 < 16) {
      writeA((kt + 1) & 1);                       // regs (tile kt+1) -> LDS
      stageB((kt + 1) * 32, (kt + 1) & 1);        // async, lands by next barrier
      if (kt + 2 < 16) loadA((kt + 2) * 32);      // full iter of latency
    }
    const unsigned short* sA = sm + (kt & 1) * 8192;
    const unsigned short* sB = sA + 4096;
    const int sw = ((quad ^ (l16 & 3)) << 3);
    short8 af[4], bf[4];
    #pragma unroll
    for (int mi = 0; mi < 4; mi++)
      af[mi] = *(const short8*)&sA[(wm * 64 + mi * 16 + l16) * 32 + sw];
    #pragma unroll
    for (int ni = 0; ni < 4; ni++)
      bf[ni] = *(const short8*)&sB[(wn * 64 + ni * 16 + l16) * 32 + sw];
    #pragma unroll
    for (int mi = 0; mi < 4; mi++)
      #pragma unroll
      for (int ni = 0; ni < 4; ni++)
        acc[mi][ni] = __builtin_amdgcn_mfma_f32_16x16x32_bf16(af[mi], bf[ni], acc[mi][ni], 0, 0, 0);
  }

  __syncthreads();  // main-loop LDS reads done; reuse sm for epilogue

  if (cls < 2) {
    // token-major C tile [128 tok][136], coalesced 128B-run readback
    const float qs = (cls == 0) ? CLOG2_ : 1.0f;   // fold softmax scale into Q
    #pragma unroll
    for (int mi = 0; mi < 4; mi++) {
      const int row0 = wm * 64 + mi * 16 + quad * 4;
      #pragma unroll
      for (int ni = 0; ni < 4; ni++) {
        const int col = wn * 64 + ni * 16 + l16;
        #pragma unroll
        for (int r = 0; r < 4; r++)
          sm[(row0 + r) * 136 + col] = f2bf(acc[mi][ni][r] * qs);
      }
    }
    __syncthreads();
    const int row = tid >> 1, half = tid & 1;
    const int t = t0 + row, bb = t >> 11, nn = t & (N_ - 1);
    const int cw = (c0 & 511) + half * 64;
    const int hh = cw >> 6;
    unsigned short* dst = ((cls == 0) ? qws : kws) +
                          ((size_t)(bb * H_ + hh) * N_ + nn) * D_;
    const unsigned short* srcp = &sm[row * 136 + half * 64];
    #pragma unroll
    for (int j = 0; j < 8; j++)
      *(uint4*)(dst + j * 8) = *(const uint4*)(srcp + j * 8);
  } else {
    // transposed C tile [128 col][136 tok], coalesced readback along n
    #pragma unroll
    for (int mi = 0; mi < 4; mi++) {
      const int tk = wm * 64 + mi * 16 + quad * 4;
      #pragma unroll
      for (int ni = 0; ni < 4; ni++) {
        const int col = wn * 64 + ni * 16 + l16;
        bs4 pk4 = pack4(acc[mi][ni][0], acc[mi][ni][1], acc[mi][ni][2], acc[mi][ni][3]);
        *(bs4*)&sm[col * 136 + tk] = pk4;
      }
    }
    __syncthreads();
    const int col = tid >> 1, half = tid & 1;
    const int cw = (c0 - 1024) + col;
    const int hh = cw >> 6, dd = cw & 63;
    const int bb = t0 >> 11, n0 = (t0 & (N_ - 1)) + half * 64;
    unsigned short* dst = vws + ((size_t)(bb * H_ + hh) * D_ + dd) * N_ + n0;
    const unsigned short* srcp = &sm[col * 136 + half * 64];
    #pragma unroll
    for (int j = 0; j < 8; j++)
      *(uint4*)(dst + j * 8) = *(const uint4*)(srcp + j * 8);
  }
}

// ---------------------------------------------------------------------------
// Kernel 2: flash attention. R4 wave layout (proven) + R10 setprio (+3us)
// R11: KVBLK 64 -> 128. 16 iterations instead of 32: per-iter fixed costs
// (barrier + vmcnt drain + gld16 issue + loop control) halved; each wave
// now runs 4 independent MFMA chains (2 rb x 2 K=32 P-fragments) for
// deeper ILP in the QK->exp2->pack->PV chain. LDS 2 x 32 KB = 64 KB ->
// still 2 blocks/CU, 16 waves/CU (occupancy invariant; avoids R6 mistake).
// All swizzle math extends by sub-tile offset only (16,64 == 0 mod 8).
// Additive kh-combine epilogue unchanged.
// ---------------------------------------------------------------------------
__global__ __launch_bounds__(512, 4) void attention_kernel(
    const unsigned short* __restrict__ qws,
    const unsigned short* __restrict__ kws,
    const unsigned short* __restrict__ vws,
    unsigned short* __restrict__ ows)
{
  __shared__ __attribute__((aligned(16))) unsigned short sm[2][16384];  // 64 KB
  __shared__ float sml[128];   // l-partials from the key-upper half

  const int lid = blockIdx.x + (blockIdx.y << 4);      // grid (16,32), 0..511
  const int swz = ((lid & 7) << 6) + (lid >> 3);       // bijective XCD chunking
  const int q0 = (swz & 15) * 128;                     // q-tile fast within chunk
  const int bh = swz >> 4;                             // 4 contiguous bh per XCD
  const int tid = threadIdx.x;
  const int wave = tid >> 6, lane = tid & 63;
  const int quad = lane >> 4, l16 = lane & 15;
  const int rbw = wave & 3;                            // row-block pair owner
  const int kh = wave >> 2;                            // key half [0,64)/[64,128)

  const unsigned short* qbase = qws + (size_t)bh * N_ * D_;
  const unsigned short* kbase = kws + (size_t)bh * N_ * D_;
  const unsigned short* vbase = vws + (size_t)bh * D_ * N_;

  // two q row-blocks per wave: rows q0 + rbw*32 + rb*16 + l16
  short8 qf[2][2];
  #pragma unroll
  for (int rb = 0; rb < 2; rb++) {
    const int qrow = q0 + rbw * 32 + rb * 16 + l16;
    #pragma unroll
    for (int kc = 0; kc < 2; kc++)
      qf[rb][kc] = *(const short8*)(qbase + (size_t)qrow * D_ + kc * 32 + quad * 8);
  }

  f32x4 ot[2][4];
  f32x4 otl[2];
  #pragma unroll
  for (int rb = 0; rb < 2; rb++) {
    #pragma unroll
    for (int db = 0; db < 4; db++) ot[rb][db] = (f32x4){0.f, 0.f, 0.f, 0.f};
    otl[rb] = (f32x4){0.f, 0.f, 0.f, 0.f};
  }
  const short8 ones8 = {(short)0x3F80, (short)0x3F80, (short)0x3F80, (short)0x3F80,
                        (short)0x3F80, (short)0x3F80, (short)0x3F80, (short)0x3F80};

  // staging: 512 lanes x 16B = 8 KB per gld16; K tile 16 KB + V tile 16 KB
  // = 4 calls per 128-key tile. Row parity preserved (64 == 0 mod 8) so the
  // read-side slot formula g^(row&7) is unchanged per 64-row sub-tile.
  const int r_ = tid >> 3;                   // 0..63
  const int gc = (tid & 7) ^ (r_ & 7);
  const unsigned short* kst = kbase + (size_t)r_ * D_ + gc * 8;
  const unsigned short* vst = vbase + (size_t)r_ * N_ + gc * 8;

  auto stage = [&](int kt, int buf) {
    const int k0 = kt * 128;
    unsigned short* Ks = &sm[buf][0];
    unsigned short* Vs = &sm[buf][8192];
    gld16(kst + (size_t)k0 * D_,        Ks + tid * 8);          // keys k0..k0+63
    gld16(kst + (size_t)(k0 + 64) * D_, Ks + 4096 + tid * 8);   // keys +64..127
    gld16(vst + k0,                     Vs + tid * 8);          // V sub-tile 0
    gld16(vst + k0 + 64,                Vs + 4096 + tid * 8);   // V sub-tile 1
  };

  const int NT = N_ / 128;   // 16
  stage(0, 0);

  for (int kt = 0; kt < NT; kt++) {
    const int cur = kt & 1;
    __syncthreads();
    if (kt + 1 < NT) stage(kt + 1, cur ^ 1);
    const unsigned short* Ks = &sm[cur][0];
    const unsigned short* Vs = &sm[cur][8192];

    // QK^T over this wave's 64-key half; each K fragment feeds both row-blocks
    f32x4 st[2][4];
    #pragma unroll
    for (int rb = 0; rb < 2; rb++)
      #pragma unroll
      for (int nb = 0; nb < 4; nb++) st[rb][nb] = (f32x4){0.f, 0.f, 0.f, 0.f};
    __builtin_amdgcn_s_setprio(1);
    #pragma unroll
    for (int kc = 0; kc < 2; kc++) {
      const int sw = (((kc * 4 + quad) ^ (l16 & 7)) << 3);
      #pragma unroll
      for (int nb = 0; nb < 4; nb++) {
        short8 kf = *(const short8*)&Ks[(kh * 64 + nb * 16 + l16) * 64 + sw];
        st[0][nb] = __builtin_amdgcn_mfma_f32_16x16x32_bf16(kf, qf[0][kc], st[0][nb], 0, 0, 0);
        st[1][nb] = __builtin_amdgcn_mfma_f32_16x16x32_bf16(kf, qf[1][kc], st[1][nb], 0, 0, 0);
      }
    }
    __builtin_amdgcn_s_setprio(0);

    // softmax numerators + two K=32 P-fragments per row-block
    short8 pA[2][2];
    #pragma unroll
    for (int rb = 0; rb < 2; rb++) {
      bs4 pf[4];
      #pragma unroll
      for (int nb = 0; nb < 4; nb++) {
        float p0 = __builtin_amdgcn_exp2f(st[rb][nb][0]);
        float p1 = __builtin_amdgcn_exp2f(st[rb][nb][1]);
        float p2 = __builtin_amdgcn_exp2f(st[rb][nb][2]);
        float p3 = __builtin_amdgcn_exp2f(st[rb][nb][3]);
        pf[nb] = pack4(p0, p1, p2, p3);
      }
      pA[rb][0] = assemble_p(pf[0], pf[1]);   // keys kh*64 +  0..31
      pA[rb][1] = assemble_p(pf[2], pf[3]);   // keys kh*64 + 32..63
    }

    // PV over this wave's 64-key half (V sub-tile kh), 2 key-groups
    #pragma unroll
    for (int h = 0; h < 2; h++) {
      const int slot = (((h * 4 + quad) ^ (l16 & 7)) << 3);
      short8 vf8[4];
      #pragma unroll
      for (int db = 0; db < 4; db++)
        vf8[db] = *(const short8*)&Vs[kh * 4096 + (db * 16 + l16) * 64 + slot];
      __builtin_amdgcn_s_setprio(1);
      #pragma unroll
      for (int rb = 0; rb < 2; rb++) {
        #pragma unroll
        for (int db = 0; db < 4; db++)
          ot[rb][db] = __builtin_amdgcn_mfma_f32_16x16x32_bf16(vf8[db], pA[rb][h], ot[rb][db], 0, 0, 0);
        otl[rb] = __builtin_amdgcn_mfma_f32_16x16x32_bf16(ones8, pA[rb][h], otl[rb], 0, 0, 0);
      }
      __builtin_amdgcn_s_setprio(0);
    }
  }

  // ---- key-half combine (additive: no running max in unshifted exp2) ----
  __syncthreads();                         // main-loop LDS traffic done
  float* Of = (float*)sm;                  // [128 q][16 f32x4 slots], swizzled
  if (kh == 1) {
    #pragma unroll
    for (int rb = 0; rb < 2; rb++) {
      const int q = rbw * 32 + rb * 16 + l16;
      #pragma unroll
      for (int db = 0; db < 4; db++) {
        const int slot = (db * 4 + quad) ^ l16;   // break 256B-stride conflict
        *(f32x4*)&Of[q * 64 + slot * 4] = ot[rb][db];
      }
      if (quad == 0) sml[q] = otl[rb][0];  // every lane's otl[.][0] == l(q=l16)
    }
  }
  __syncthreads();
  bs4 pk[2][4];
  if (kh == 0) {
    #pragma unroll
    for (int rb = 0; rb < 2; rb++) {
      const int q = rbw * 32 + rb * 16 + l16;
      const float inv = 1.f / (otl[rb][0] + sml[q]);
      #pragma unroll
      for (int db = 0; db < 4; db++) {
        const int slot = (db * 4 + quad) ^ l16;
        f32x4 p = *(const f32x4*)&Of[q * 64 + slot * 4];
        pk[rb][db] = pack4((ot[rb][db][0] + p[0]) * inv, (ot[rb][db][1] + p[1]) * inv,
                           (ot[rb][db][2] + p[2]) * inv, (ot[rb][db][3] + p[3]) * inv);
      }
    }
  }
  __syncthreads();                         // all Of reads done; reuse as overlay
  unsigned short* Os = (unsigned short*)sm;   // 128 x 72 overlay (18 KB)
  if (kh == 0) {
    #pragma unroll
    for (int rb = 0; rb < 2; rb++)
      #pragma unroll
      for (int db = 0; db < 4; db++)
        *(bs4*)&Os[(rbw * 32 + rb * 16 + l16) * 72 + db * 16 + quad * 4] = pk[rb][db];
  }
  __syncthreads();
  // coalesced global copy: 512 threads x 32B
  const int b_ = bh >> 3, h_ = bh & 7;
  const int qloc = tid >> 2, chunk = tid & 3;
  unsigned short* dst = ows + ((size_t)b_ * N_ + q0 + qloc) * (H_ * D_) + h_ * 64 + chunk * 16;
  const unsigned short* srcp = &Os[qloc * 72 + chunk * 16];
  *(uint4*)dst = *(const uint4*)srcp;
  *(uint4*)(dst + 8) = *(const uint4*)(srcp + 8);
}

// ---------------------------------------------------------------------------
// Kernel 3: output projection. 128x64 tile, BK=32, DOUBLE-BUFFERED
// gld16 staging for BOTH operands (bf16 ows + bf16 wobf).
// fp32 out + bias, 64B-run stores. XCD-chunked swizzle (bijective 512%8==0).
// ---------------------------------------------------------------------------
__global__ __launch_bounds__(256) void out_gemm_kernel(
    const unsigned short* __restrict__ ain, const unsigned short* __restrict__ wobf,
    const float* __restrict__ bo, float* __restrict__ y)
{
  // buf b at sm + b*6144: A 4096 | B 2048 shorts; total 12288 shorts = 24 KB
  __shared__ __attribute__((aligned(16))) unsigned short sm[12288];

  const int lid = blockIdx.x + (blockIdx.y << 6);      // grid (64,8), 0..511
  const int swz = ((lid & 7) << 6) + (lid >> 3);       // bijective XCD chunking
  const int t0 = (swz >> 3) * 128;
  const int c0 = (swz & 7) * 64;
  const int tid = threadIdx.x;
  const int wave = tid >> 6, lane = tid & 63;
  const int quad = lane >> 4, l16 = lane & 15;

  const int r_ = tid >> 2;
  const int gc = (tid & 3) ^ (r_ & 3);
  const unsigned short* abase = ain  + (size_t)(t0 + r_) * IN_ + gc * 8;
  const unsigned short* bbase = wobf + (size_t)(c0 + r_) * IN_ + gc * 8;

  auto stage = [&](int k0, int buf) {
    unsigned short* sA = sm + buf * 6144;
    unsigned short* sB = sA + 4096;
    gld16(abase + k0,            sA + tid * 8);
    gld16(abase + 64 * IN_ + k0, sA + 2048 + tid * 8);
    gld16(bbase + k0,            sB + tid * 8);     // B: 64 rows x 4 granules = 256 slots
  };

  f32x4 acc[2][4];
  #pragma unroll
  for (int i = 0; i < 2; i++)
    #pragma unroll
    for (int j = 0; j < 4; j++) acc[i][j] = (f32x4){0.f, 0.f, 0.f, 0.f};

  stage(0, 0);

  for (int kt = 0; kt < 16; kt++) {
    const int cur = kt & 1;
    __syncthreads();
    if (kt + 1 < 16) stage((kt + 1) * 32, cur ^ 1);
    const unsigned short* sA = sm + cur * 6144;
    const unsigned short* sB = sA + 4096;
    const int sw = ((quad ^ (l16 & 3)) << 3);
    short8 af[2], bf[4];
    #pragma unroll
    for (int mi = 0; mi < 2; mi++)
      af[mi] = *(const short8*)&sA[(wave * 32 + mi * 16 + l16) * 32 + sw];
    #pragma unroll
    for (int ni = 0; ni < 4; ni++)
      bf[ni] = *(const short8*)&sB[(ni * 16 + l16) * 32 + sw];
    #pragma unroll
    for (int mi = 0; mi < 2; mi++)
      #pragma unroll
      for (int ni = 0; ni < 4; ni++)
        acc[mi][ni] = __builtin_amdgcn_mfma_f32_16x16x32_bf16(af[mi], bf[ni], acc[mi][ni], 0, 0, 0);
  }

  #pragma unroll
  for (int mi = 0; mi < 2; mi++) {
    const int t = t0 + wave * 32 + mi * 16 + quad * 4;
    #pragma unroll
    for (int ni = 0; ni < 4; ni++) {
      const int c = c0 + ni * 16 + l16;
      const float bias = bo[c];
      float* dst = y + (size_t)t * IN_ + c;
      dst[0]        = acc[mi][ni][0] + bias;
      dst[IN_]      = acc[mi][ni][1] + bias;
      dst[2 * IN_]  = acc[mi][ni][2] + bias;
      dst[3 * IN_]  = acc[mi][ni][3] + bias;
    }
  }
}

extern "C" void kernel_launch(void* const* d_in, const int* in_sizes, int n_in,
                              void* d_out, int out_size, void* d_ws, size_t ws_size,
                              hipStream_t stream) {
  const float* x   = (const float*)d_in[0];
  const float* Wq  = (const float*)d_in[1];
  const float* Wkv = (const float*)d_in[2];
  const float* Wo  = (const float*)d_in[3];
  const float* bo  = (const float*)d_in[4];
  float* out = (float*)d_out;

  // ws (shorts): qws 4M | kws 4M | vws 4M | ows 4M | wbf 768K | wobf 256K
  unsigned short* qws  = (unsigned short*)d_ws;
  unsigned short* kws  = qws + (size_t)TOK_ * 512;
  unsigned short* vws  = kws + (size_t)TOK_ * 512;
  unsigned short* ows  = vws + (size_t)TOK_ * 512;
  unsigned short* wbf  = ows + (size_t)TOK_ * 512;       // [Wq 512 | Wkv 1024] x 512
  unsigned short* wobf = wbf + (size_t)1536 * 512;

  conv_w_kernel<<<dim3(512), 256, 0, stream>>>(Wq, Wkv, Wo, wbf, wobf);
  qkv_gemm_kernel<<<dim3(TOK_ / 128, 1536 / 128), 256, 0, stream>>>(x, wbf, qws, kws, vws);
  attention_kernel<<<dim3(N_ / 128, B_ * H_), 512, 0, stream>>>(qws, kws, vws, ows);
  out_gemm_kernel<<<dim3(TOK_ / 128, 512 / 64), 256, 0, stream>>>(ows, wobf, bo, out);
}

// Round 12
// 149.964 us; speedup vs baseline: 1.0026x; 1.0026x over previous
//
#include <hip/hip_runtime.h>
#include <hip/hip_bf16.h>

#define H_ 8
#define D_ 64
#define IN_ 512
#define B_ 4
#define N_ 2048
#define TOK_ (B_*N_)
// softmax in exp2 domain: scale * log2(e) (folded into Q at projection time)
#define CLOG2_ 0.18033688011112042f

typedef __attribute__((ext_vector_type(8))) short short8;
typedef __attribute__((ext_vector_type(4))) short bs4;
typedef __attribute__((ext_vector_type(4))) float f32x4;

__device__ __forceinline__ unsigned short f2bf(float f) {
  unsigned int u = __float_as_uint(f);
  u += 0x7FFFu + ((u >> 16) & 1u);
  return (unsigned short)(u >> 16);
}

// packed converts: v_cvt_pk_bf16_f32
__device__ __forceinline__ short8 cvt8(const float4 a, const float4 b) {
  union { short8 v; __hip_bfloat162 h[4]; } z;
  z.h[0] = __float22bfloat162_rn(make_float2(a.x, a.y));
  z.h[1] = __float22bfloat162_rn(make_float2(a.z, a.w));
  z.h[2] = __float22bfloat162_rn(make_float2(b.x, b.y));
  z.h[3] = __float22bfloat162_rn(make_float2(b.z, b.w));
  return z.v;
}

__device__ __forceinline__ bs4 pack4(float a, float b, float c, float d) {
  union { bs4 v; __hip_bfloat162 h[2]; } z;
  z.h[0] = __float22bfloat162_rn(make_float2(a, b));
  z.h[1] = __float22bfloat162_rn(make_float2(c, d));
  return z.v;
}

// Reassemble two K=16 P-fragments (keys nb*16+quad*4+r layout) into one K=32
// B-fragment (keys quad*8+j layout) with 4 lane-swaps.
__device__ __forceinline__ short8 assemble_p(bs4 pa, bs4 pb) {
  union { bs4 v; unsigned int w[2]; } A, B;
  A.v = pa; B.v = pb;
  auto s0 = __builtin_amdgcn_permlane32_swap(A.w[0], B.w[0], false, false);
  auto s1 = __builtin_amdgcn_permlane32_swap(A.w[1], B.w[1], false, false);
  auto t0 = __builtin_amdgcn_permlane16_swap(s0[0], s0[1], false, false);
  auto t1 = __builtin_amdgcn_permlane16_swap(s1[0], s1[1], false, false);
  union { short8 v; unsigned int w[4]; } R;
  R.w[0] = t0[0];   // j=0,1
  R.w[1] = t1[0];   // j=2,3
  R.w[2] = t0[1];   // j=4,5
  R.w[3] = t1[1];   // j=6,7
  return R.v;
}

// async global->LDS, 16B per lane; dest = wave-uniform base + lane*16
__device__ __forceinline__ void gld16(const unsigned short* g, unsigned short* l) {
  __builtin_amdgcn_global_load_lds(
      (const __attribute__((address_space(1))) void*)g,
      (__attribute__((address_space(3))) void*)l, 16, 0, 0);
}

// ---------------------------------------------------------------------------
// Kernel 0: WEIGHTS-ONLY fp32 -> bf16 convert (Wq, Wkv, Wo). 512 blocks.
// ---------------------------------------------------------------------------
__global__ __launch_bounds__(256) void conv_w_kernel(
    const float* __restrict__ Wq, const float* __restrict__ Wkv,
    const float* __restrict__ Wo,
    unsigned short* __restrict__ wbf, unsigned short* __restrict__ wobf)
{
  const int b = blockIdx.x;
  const float* src;
  unsigned short* dst;
  size_t base;
  if (b < 128)       { src = Wq;  dst = wbf;             base = (size_t)b * 2048; }
  else if (b < 384)  { src = Wkv; dst = wbf + 512 * 512; base = (size_t)(b - 128) * 2048; }
  else               { src = Wo;  dst = wobf;            base = (size_t)(b - 384) * 2048; }
  size_t i = base + (size_t)threadIdx.x * 8;
  float4 a = *(const float4*)(src + i);
  float4 c = *(const float4*)(src + i + 4);
  *(short8*)(dst + i) = cvt8(a, c);
}

// ---------------------------------------------------------------------------
// Kernel 1: QKV projection. A = x fp32 reg-staged (load->cvt_pk->ds_write);
// B = weights bf16 via gld16 (L2-fit). 128x128 tile, BK=32, double-buffered.
// R12: counted vmcnt + raw barrier (T4). The old __syncthreads drained
// vmcnt(0), stalling on loadA(kt+2)'s 4 fp32 loads issued only ~300 cyc
// earlier — qkv's iters are SHORT (~300 cyc work) vs L2 latency, so this
// drain binds (unlike attention, R5). vmcnt retires in issue order: the 2
// gld16 (tile kt, needed now) precede the 4 loadA (tile kt+2, needed next
// iter), so vmcnt(4) guarantees the gld16s landed while loadA flies.
// kt=15 edge: no loadA outstanding -> vmcnt(0). lgkmcnt(0) keeps ds_write
// visibility across the barrier.
// Q pre-scaled by CLOG2_. Q,K -> [b,h,n,d]; V -> [b,h,d,n]. LDS epilogues.
// XCD-chunked block swizzle (T1, bijective: 768%8==0).
// ---------------------------------------------------------------------------
__global__ __launch_bounds__(256) void qkv_gemm_kernel(
    const float* __restrict__ x, const unsigned short* __restrict__ wbf,
    unsigned short* __restrict__ qws, unsigned short* __restrict__ kws,
    unsigned short* __restrict__ vws)
{
  // staging: buf b at sm + b*8192 (A 4096 | B 4096 shorts); epilogue overlay 128*136
  __shared__ __attribute__((aligned(16))) unsigned short sm[128 * 136];

  const int lid = blockIdx.x + (blockIdx.y << 6);      // grid (64,12), 0..767
  const int swz = (lid & 7) * 96 + (lid >> 3);         // bijective XCD chunking
  const int t0 = (swz / 12) * 128;
  const int c0 = (swz % 12) * 128;                     // 0..1535 over [Wq|Wkv] rows
  const int cls = c0 >> 9;                             // 0=q 1=k 2=v

  const int tid = threadIdx.x;
  const int wave = tid >> 6, lane = tid & 63;
  const int quad = lane >> 4, l16 = lane & 15;
  const int wm = wave >> 1, wn = wave & 1;

  // staging source: row r = g*64 + tid>>2, granule gc = (tid&3)^(r&3)
  const int r_ = tid >> 2;
  const int gc = (tid & 3) ^ (r_ & 3);
  const float* asrc = x + (size_t)(t0 + r_) * IN_ + gc * 8;
  const unsigned short* bbase = wbf + (size_t)(c0 + r_) * IN_ + gc * 8;

  float4 ra[4];
  auto loadA = [&](int k0) {
    ra[0] = *(const float4*)(asrc + k0);
    ra[1] = *(const float4*)(asrc + k0 + 4);
    ra[2] = *(const float4*)(asrc + 64 * IN_ + k0);
    ra[3] = *(const float4*)(asrc + 64 * IN_ + k0 + 4);
  };
  auto writeA = [&](int buf) {
    unsigned short* sA = sm + buf * 8192;
    *(short8*)(sA + tid * 8)        = cvt8(ra[0], ra[1]);
    *(short8*)(sA + 2048 + tid * 8) = cvt8(ra[2], ra[3]);
  };
  auto stageB = [&](int k0, int buf) {
    unsigned short* sB = sm + buf * 8192 + 4096;
    gld16(bbase + k0,            sB + tid * 8);
    gld16(bbase + 64 * IN_ + k0, sB + 2048 + tid * 8);
  };

  f32x4 acc[4][4];
  #pragma unroll
  for (int i = 0; i < 4; i++)
    #pragma unroll
    for (int j = 0; j < 4; j++) acc[i][j] = (f32x4){0.f, 0.f, 0.f, 0.f};

  loadA(0); writeA(0); stageB(0, 0); loadA(32);   // regs hold A-tile 1

  for (int kt = 0; kt < 16; kt++) {
    // need: buf[kt&1] B gld16 (2 oldest vm ops) + A ds_writes visible.
    // allow: loadA(kt+1)'s 4 fp32 loads to stay in flight.
    if (kt < 15) asm volatile("s_waitcnt vmcnt(4) lgkmcnt(0)" ::: "memory");
    else         asm volatile("s_waitcnt vmcnt(0) lgkmcnt(0)" ::: "memory");
    __builtin_amdgcn_s_barrier();
    if (kt + 1 < 16) {
      writeA((kt + 1) & 1);                       // regs (tile kt+1) -> LDS
      stageB((kt + 1) * 32, (kt + 1) & 1);        // async, lands by next barrier
      if (kt + 2 < 16) loadA((kt + 2) * 32);      // full iter of latency
    }
    const unsigned short* sA = sm + (kt & 1) * 8192;
    const unsigned short* sB = sA + 4096;
    const int sw = ((quad ^ (l16 & 3)) << 3);
    short8 af[4], bf[4];
    #pragma unroll
    for (int mi = 0; mi < 4; mi++)
      af[mi] = *(const short8*)&sA[(wm * 64 + mi * 16 + l16) * 32 + sw];
    #pragma unroll
    for (int ni = 0; ni < 4; ni++)
      bf[ni] = *(const short8*)&sB[(wn * 64 + ni * 16 + l16) * 32 + sw];
    #pragma unroll
    for (int mi = 0; mi < 4; mi++)
      #pragma unroll
      for (int ni = 0; ni < 4; ni++)
        acc[mi][ni] = __builtin_amdgcn_mfma_f32_16x16x32_bf16(af[mi], bf[ni], acc[mi][ni], 0, 0, 0);
  }

  __syncthreads();  // main-loop LDS reads done; reuse sm for epilogue

  if (cls < 2) {
    // token-major C tile [128 tok][136], coalesced 128B-run readback
    const float qs = (cls == 0) ? CLOG2_ : 1.0f;   // fold softmax scale into Q
    #pragma unroll
    for (int mi = 0; mi < 4; mi++) {
      const int row0 = wm * 64 + mi * 16 + quad * 4;
      #pragma unroll
      for (int ni = 0; ni < 4; ni++) {
        const int col = wn * 64 + ni * 16 + l16;
        #pragma unroll
        for (int r = 0; r < 4; r++)
          sm[(row0 + r) * 136 + col] = f2bf(acc[mi][ni][r] * qs);
      }
    }
    __syncthreads();
    const int row = tid >> 1, half = tid & 1;
    const int t = t0 + row, bb = t >> 11, nn = t & (N_ - 1);
    const int cw = (c0 & 511) + half * 64;
    const int hh = cw >> 6;
    unsigned short* dst = ((cls == 0) ? qws : kws) +
                          ((size_t)(bb * H_ + hh) * N_ + nn) * D_;
    const unsigned short* srcp = &sm[row * 136 + half * 64];
    #pragma unroll
    for (int j = 0; j < 8; j++)
      *(uint4*)(dst + j * 8) = *(const uint4*)(srcp + j * 8);
  } else {
    // transposed C tile [128 col][136 tok], coalesced readback along n
    #pragma unroll
    for (int mi = 0; mi < 4; mi++) {
      const int tk = wm * 64 + mi * 16 + quad * 4;
      #pragma unroll
      for (int ni = 0; ni < 4; ni++) {
        const int col = wn * 64 + ni * 16 + l16;
        bs4 pk4 = pack4(acc[mi][ni][0], acc[mi][ni][1], acc[mi][ni][2], acc[mi][ni][3]);
        *(bs4*)&sm[col * 136 + tk] = pk4;
      }
    }
    __syncthreads();
    const int col = tid >> 1, half = tid & 1;
    const int cw = (c0 - 1024) + col;
    const int hh = cw >> 6, dd = cw & 63;
    const int bb = t0 >> 11, n0 = (t0 & (N_ - 1)) + half * 64;
    unsigned short* dst = vws + ((size_t)(bb * H_ + hh) * D_ + dd) * N_ + n0;
    const unsigned short* srcp = &sm[col * 136 + half * 64];
    #pragma unroll
    for (int j = 0; j < 8; j++)
      *(uint4*)(dst + j * 8) = *(const uint4*)(srcp + j * 8);
  }
}

// ---------------------------------------------------------------------------
// Kernel 2: flash attention. R4 wave layout + R10 setprio + R11 KVBLK=128
// (measured best: 43.7 us, MfmaUtil 34%). Unchanged this round.
// ---------------------------------------------------------------------------
__global__ __launch_bounds__(512, 4) void attention_kernel(
    const unsigned short* __restrict__ qws,
    const unsigned short* __restrict__ kws,
    const unsigned short* __restrict__ vws,
    unsigned short* __restrict__ ows)
{
  __shared__ __attribute__((aligned(16))) unsigned short sm[2][16384];  // 64 KB
  __shared__ float sml[128];   // l-partials from the key-upper half

  const int lid = blockIdx.x + (blockIdx.y << 4);      // grid (16,32), 0..511
  const int swz = ((lid & 7) << 6) + (lid >> 3);       // bijective XCD chunking
  const int q0 = (swz & 15) * 128;                     // q-tile fast within chunk
  const int bh = swz >> 4;                             // 4 contiguous bh per XCD
  const int tid = threadIdx.x;
  const int wave = tid >> 6, lane = tid & 63;
  const int quad = lane >> 4, l16 = lane & 15;
  const int rbw = wave & 3;                            // row-block pair owner
  const int kh = wave >> 2;                            // key half [0,64)/[64,128)

  const unsigned short* qbase = qws + (size_t)bh * N_ * D_;
  const unsigned short* kbase = kws + (size_t)bh * N_ * D_;
  const unsigned short* vbase = vws + (size_t)bh * D_ * N_;

  // two q row-blocks per wave: rows q0 + rbw*32 + rb*16 + l16
  short8 qf[2][2];
  #pragma unroll
  for (int rb = 0; rb < 2; rb++) {
    const int qrow = q0 + rbw * 32 + rb * 16 + l16;
    #pragma unroll
    for (int kc = 0; kc < 2; kc++)
      qf[rb][kc] = *(const short8*)(qbase + (size_t)qrow * D_ + kc * 32 + quad * 8);
  }

  f32x4 ot[2][4];
  f32x4 otl[2];
  #pragma unroll
  for (int rb = 0; rb < 2; rb++) {
    #pragma unroll
    for (int db = 0; db < 4; db++) ot[rb][db] = (f32x4){0.f, 0.f, 0.f, 0.f};
    otl[rb] = (f32x4){0.f, 0.f, 0.f, 0.f};
  }
  const short8 ones8 = {(short)0x3F80, (short)0x3F80, (short)0x3F80, (short)0x3F80,
                        (short)0x3F80, (short)0x3F80, (short)0x3F80, (short)0x3F80};

  // staging: 512 lanes x 16B = 8 KB per gld16; K tile 16 KB + V tile 16 KB
  // = 4 calls per 128-key tile. Row parity preserved (64 == 0 mod 8).
  const int r_ = tid >> 3;                   // 0..63
  const int gc = (tid & 7) ^ (r_ & 7);
  const unsigned short* kst = kbase + (size_t)r_ * D_ + gc * 8;
  const unsigned short* vst = vbase + (size_t)r_ * N_ + gc * 8;

  auto stage = [&](int kt, int buf) {
    const int k0 = kt * 128;
    unsigned short* Ks = &sm[buf][0];
    unsigned short* Vs = &sm[buf][8192];
    gld16(kst + (size_t)k0 * D_,        Ks + tid * 8);          // keys k0..k0+63
    gld16(kst + (size_t)(k0 + 64) * D_, Ks + 4096 + tid * 8);   // keys +64..127
    gld16(vst + k0,                     Vs + tid * 8);          // V sub-tile 0
    gld16(vst + k0 + 64,                Vs + 4096 + tid * 8);   // V sub-tile 1
  };

  const int NT = N_ / 128;   // 16
  stage(0, 0);

  for (int kt = 0; kt < NT; kt++) {
    const int cur = kt & 1;
    __syncthreads();
    if (kt + 1 < NT) stage(kt + 1, cur ^ 1);
    const unsigned short* Ks = &sm[cur][0];
    const unsigned short* Vs = &sm[cur][8192];

    // QK^T over this wave's 64-key half; each K fragment feeds both row-blocks
    f32x4 st[2][4];
    #pragma unroll
    for (int rb = 0; rb < 2; rb++)
      #pragma unroll
      for (int nb = 0; nb < 4; nb++) st[rb][nb] = (f32x4){0.f, 0.f, 0.f, 0.f};
    __builtin_amdgcn_s_setprio(1);
    #pragma unroll
    for (int kc = 0; kc < 2; kc++) {
      const int sw = (((kc * 4 + quad) ^ (l16 & 7)) << 3);
      #pragma unroll
      for (int nb = 0; nb < 4; nb++) {
        short8 kf = *(const short8*)&Ks[(kh * 64 + nb * 16 + l16) * 64 + sw];
        st[0][nb] = __builtin_amdgcn_mfma_f32_16x16x32_bf16(kf, qf[0][kc], st[0][nb], 0, 0, 0);
        st[1][nb] = __builtin_amdgcn_mfma_f32_16x16x32_bf16(kf, qf[1][kc], st[1][nb], 0, 0, 0);
      }
    }
    __builtin_amdgcn_s_setprio(0);

    // softmax numerators + two K=32 P-fragments per row-block
    short8 pA[2][2];
    #pragma unroll
    for (int rb = 0; rb < 2; rb++) {
      bs4 pf[4];
      #pragma unroll
      for (int nb = 0; nb < 4; nb++) {
        float p0 = __builtin_amdgcn_exp2f(st[rb][nb][0]);
        float p1 = __builtin_amdgcn_exp2f(st[rb][nb][1]);
        float p2 = __builtin_amdgcn_exp2f(st[rb][nb][2]);
        float p3 = __builtin_amdgcn_exp2f(st[rb][nb][3]);
        pf[nb] = pack4(p0, p1, p2, p3);
      }
      pA[rb][0] = assemble_p(pf[0], pf[1]);   // keys kh*64 +  0..31
      pA[rb][1] = assemble_p(pf[2], pf[3]);   // keys kh*64 + 32..63
    }

    // PV over this wave's 64-key half (V sub-tile kh), 2 key-groups
    #pragma unroll
    for (int h = 0; h < 2; h++) {
      const int slot = (((h * 4 + quad) ^ (l16 & 7)) << 3);
      short8 vf8[4];
      #pragma unroll
      for (int db = 0; db < 4; db++)
        vf8[db] = *(const short8*)&Vs[kh * 4096 + (db * 16 + l16) * 64 + slot];
      __builtin_amdgcn_s_setprio(1);
      #pragma unroll
      for (int rb = 0; rb < 2; rb++) {
        #pragma unroll
        for (int db = 0; db < 4; db++)
          ot[rb][db] = __builtin_amdgcn_mfma_f32_16x16x32_bf16(vf8[db], pA[rb][h], ot[rb][db], 0, 0, 0);
        otl[rb] = __builtin_amdgcn_mfma_f32_16x16x32_bf16(ones8, pA[rb][h], otl[rb], 0, 0, 0);
      }
      __builtin_amdgcn_s_setprio(0);
    }
  }

  // ---- key-half combine (additive: no running max in unshifted exp2) ----
  __syncthreads();                         // main-loop LDS traffic done
  float* Of = (float*)sm;                  // [128 q][16 f32x4 slots], swizzled
  if (kh == 1) {
    #pragma unroll
    for (int rb = 0; rb < 2; rb++) {
      const int q = rbw * 32 + rb * 16 + l16;
      #pragma unroll
      for (int db = 0; db < 4; db++) {
        const int slot = (db * 4 + quad) ^ l16;   // break 256B-stride conflict
        *(f32x4*)&Of[q * 64 + slot * 4] = ot[rb][db];
      }
      if (quad == 0) sml[q] = otl[rb][0];  // every lane's otl[.][0] == l(q=l16)
    }
  }
  __syncthreads();
  bs4 pk[2][4];
  if (kh == 0) {
    #pragma unroll
    for (int rb = 0; rb < 2; rb++) {
      const int q = rbw * 32 + rb * 16 + l16;
      const float inv = 1.f / (otl[rb][0] + sml[q]);
      #pragma unroll
      for (int db = 0; db < 4; db++) {
        const int slot = (db * 4 + quad) ^ l16;
        f32x4 p = *(const f32x4*)&Of[q * 64 + slot * 4];
        pk[rb][db] = pack4((ot[rb][db][0] + p[0]) * inv, (ot[rb][db][1] + p[1]) * inv,
                           (ot[rb][db][2] + p[2]) * inv, (ot[rb][db][3] + p[3]) * inv);
      }
    }
  }
  __syncthreads();                         // all Of reads done; reuse as overlay
  unsigned short* Os = (unsigned short*)sm;   // 128 x 72 overlay (18 KB)
  if (kh == 0) {
    #pragma unroll
    for (int rb = 0; rb < 2; rb++)
      #pragma unroll
      for (int db = 0; db < 4; db++)
        *(bs4*)&Os[(rbw * 32 + rb * 16 + l16) * 72 + db * 16 + quad * 4] = pk[rb][db];
  }
  __syncthreads();
  // coalesced global copy: 512 threads x 32B
  const int b_ = bh >> 3, h_ = bh & 7;
  const int qloc = tid >> 2, chunk = tid & 3;
  unsigned short* dst = ows + ((size_t)b_ * N_ + q0 + qloc) * (H_ * D_) + h_ * 64 + chunk * 16;
  const unsigned short* srcp = &Os[qloc * 72 + chunk * 16];
  *(uint4*)dst = *(const uint4*)srcp;
  *(uint4*)(dst + 8) = *(const uint4*)(srcp + 8);
}

// ---------------------------------------------------------------------------
// Kernel 3: output projection. 128x64 tile, BK=32, DOUBLE-BUFFERED
// gld16 staging for BOTH operands (bf16 ows + bf16 wobf). Its barrier drain
// only waits on loads needed next iter (all 3 gld16) — already minimal.
// fp32 out + bias, 64B-run stores. XCD-chunked swizzle (bijective 512%8==0).
// ---------------------------------------------------------------------------
__global__ __launch_bounds__(256) void out_gemm_kernel(
    const unsigned short* __restrict__ ain, const unsigned short* __restrict__ wobf,
    const float* __restrict__ bo, float* __restrict__ y)
{
  // buf b at sm + b*6144: A 4096 | B 2048 shorts; total 12288 shorts = 24 KB
  __shared__ __attribute__((aligned(16))) unsigned short sm[12288];

  const int lid = blockIdx.x + (blockIdx.y << 6);      // grid (64,8), 0..511
  const int swz = ((lid & 7) << 6) + (lid >> 3);       // bijective XCD chunking
  const int t0 = (swz >> 3) * 128;
  const int c0 = (swz & 7) * 64;
  const int tid = threadIdx.x;
  const int wave = tid >> 6, lane = tid & 63;
  const int quad = lane >> 4, l16 = lane & 15;

  const int r_ = tid >> 2;
  const int gc = (tid & 3) ^ (r_ & 3);
  const unsigned short* abase = ain  + (size_t)(t0 + r_) * IN_ + gc * 8;
  const unsigned short* bbase = wobf + (size_t)(c0 + r_) * IN_ + gc * 8;

  auto stage = [&](int k0, int buf) {
    unsigned short* sA = sm + buf * 6144;
    unsigned short* sB = sA + 4096;
    gld16(abase + k0,            sA + tid * 8);
    gld16(abase + 64 * IN_ + k0, sA + 2048 + tid * 8);
    gld16(bbase + k0,            sB + tid * 8);     // B: 64 rows x 4 granules = 256 slots
  };

  f32x4 acc[2][4];
  #pragma unroll
  for (int i = 0; i < 2; i++)
    #pragma unroll
    for (int j = 0; j < 4; j++) acc[i][j] = (f32x4){0.f, 0.f, 0.f, 0.f};

  stage(0, 0);

  for (int kt = 0; kt < 16; kt++) {
    const int cur = kt & 1;
    __syncthreads();
    if (kt + 1 < 16) stage((kt + 1) * 32, cur ^ 1);
    const unsigned short* sA = sm + cur * 6144;
    const unsigned short* sB = sA + 4096;
    const int sw = ((quad ^ (l16 & 3)) << 3);
    short8 af[2], bf[4];
    #pragma unroll
    for (int mi = 0; mi < 2; mi++)
      af[mi] = *(const short8*)&sA[(wave * 32 + mi * 16 + l16) * 32 + sw];
    #pragma unroll
    for (int ni = 0; ni < 4; ni++)
      bf[ni] = *(const short8*)&sB[(ni * 16 + l16) * 32 + sw];
    #pragma unroll
    for (int mi = 0; mi < 2; mi++)
      #pragma unroll
      for (int ni = 0; ni < 4; ni++)
        acc[mi][ni] = __builtin_amdgcn_mfma_f32_16x16x32_bf16(af[mi], bf[ni], acc[mi][ni], 0, 0, 0);
  }

  #pragma unroll
  for (int mi = 0; mi < 2; mi++) {
    const int t = t0 + wave * 32 + mi * 16 + quad * 4;
    #pragma unroll
    for (int ni = 0; ni < 4; ni++) {
      const int c = c0 + ni * 16 + l16;
      const float bias = bo[c];
      float* dst = y + (size_t)t * IN_ + c;
      dst[0]        = acc[mi][ni][0] + bias;
      dst[IN_]      = acc[mi][ni][1] + bias;
      dst[2 * IN_]  = acc[mi][ni][2] + bias;
      dst[3 * IN_]  = acc[mi][ni][3] + bias;
    }
  }
}

extern "C" void kernel_launch(void* const* d_in, const int* in_sizes, int n_in,
                              void* d_out, int out_size, void* d_ws, size_t ws_size,
                              hipStream_t stream) {
  const float* x   = (const float*)d_in[0];
  const float* Wq  = (const float*)d_in[1];
  const float* Wkv = (const float*)d_in[2];
  const float* Wo  = (const float*)d_in[3];
  const float* bo  = (const float*)d_in[4];
  float* out = (float*)d_out;

  // ws (shorts): qws 4M | kws 4M | vws 4M | ows 4M | wbf 768K | wobf 256K
  unsigned short* qws  = (unsigned short*)d_ws;
  unsigned short* kws  = qws + (size_t)TOK_ * 512;
  unsigned short* vws  = kws + (size_t)TOK_ * 512;
  unsigned short* ows  = vws + (size_t)TOK_ * 512;
  unsigned short* wbf  = ows + (size_t)TOK_ * 512;       // [Wq 512 | Wkv 1024] x 512
  unsigned short* wobf = wbf + (size_t)1536 * 512;

  conv_w_kernel<<<dim3(512), 256, 0, stream>>>(Wq, Wkv, Wo, wbf, wobf);
  qkv_gemm_kernel<<<dim3(TOK_ / 128, 1536 / 128), 256, 0, stream>>>(x, wbf, qws, kws, vws);
  attention_kernel<<<dim3(N_ / 128, B_ * H_), 512, 0, stream>>>(qws, kws, vws, ows);
  out_gemm_kernel<<<dim3(TOK_ / 128, 512 / 64), 256, 0, stream>>>(ows, wobf, bo, out);
}